// Round 3
// baseline (2304.605 us; speedup 1.0000x reference)
//
#include <hip/hip_runtime.h>

#define SEQ 4096
#define BATCH 512
#define INP 8
#define HID 30

typedef unsigned uint2v __attribute__((ext_vector_type(2)));

__device__ __forceinline__ float sigmoid_f(float v) {
    return __builtin_amdgcn_rcpf(1.0f + __expf(-v));
}

// v_permlane32_swap with vdst = vsrc = v:
//   returns {lo_rep = [v_lo | v_lo], hi_rep = [v_hi | v_hi]}
__device__ __forceinline__ void rep_halves(float v, float& lo_rep, float& hi_rep) {
#if __has_builtin(__builtin_amdgcn_permlane32_swap)
    uint2v r = __builtin_amdgcn_permlane32_swap(
        __float_as_uint(v), __float_as_uint(v), false, false);
    lo_rep = __uint_as_float(r.x);
    hi_rep = __uint_as_float(r.y);
#else
    float other = __shfl_xor(v, 32, 64);
    bool hi = (threadIdx.x & 32) != 0;
    lo_rep = hi ? other : v;
    hi_rep = hi ? v : other;
#endif
}

// One wave (64 lanes) per batch chain. No LDS.
// lane = j      (j<30): gate rows i_j (A) and g_j (B)
// lane = 32+j   (j<30): gate rows f_j (A) and o_j (B)
// h state lives in 30 SGPRs (v_readlane broadcast); gate FMAs are
// v_fma_f32 vdst, sgpr, vgpr, vacc (one SGPR source — legal).
// amdgpu_waves_per_eu(1,1): full 256-VGPR budget so the 76 weight regs
// stay resident (round-2 build allocated only 60 VGPRs -> per-step
// weight reloads on the critical path).
__global__ __launch_bounds__(64)
__attribute__((amdgpu_waves_per_eu(1, 1)))
void lstm_chain_kernel(
    const float* __restrict__ x,     // [SEQ,BATCH,INP]
    const float* __restrict__ W_ih,  // [4H, INP]
    const float* __restrict__ W_hh,  // [4H, HID]
    const float* __restrict__ b_ih,  // [4H]
    const float* __restrict__ b_hh,  // [4H]
    const float* __restrict__ W_lin, // [1, HID]
    const float* __restrict__ b_lin, // [1]
    float* __restrict__ out)         // [SEQ,BATCH,1]
{
    const int lane = threadIdx.x;
    const int b    = blockIdx.x;
    const int j    = lane & 31;
    const int half = lane >> 5;
    const int jc   = j < HID ? j : HID - 1;
    const int ra   = half * HID + jc;            // i (half0) / f (half1)
    const int rb   = 2 * HID + half * HID + jc;  // g (half0) / o (half1)

    // ---- per-lane constant weights, pinned into VGPRs ----
    float wih_a[INP], wih_b[INP];
#pragma unroll
    for (int i = 0; i < INP; ++i) {
        float wa = W_ih[ra * INP + i];
        float wb = W_ih[rb * INP + i];
        asm volatile("" : "+v"(wa));
        asm volatile("" : "+v"(wb));
        wih_a[i] = wa;
        wih_b[i] = wb;
    }
    float whh_a[HID], whh_b[HID];
#pragma unroll
    for (int k = 0; k < HID; ++k) {
        float wa = W_hh[ra * HID + k];
        float wb = W_hh[rb * HID + k];
        asm volatile("" : "+v"(wa));
        asm volatile("" : "+v"(wb));
        whh_a[k] = wa;
        whh_b[k] = wb;
    }
    const float bias_a = b_ih[ra] + b_hh[ra];
    const float bias_b = b_ih[rb] + b_hh[rb];
    const float blin   = b_lin[0];
    // per-lane output weight (1 VGPR); lanes 30,31 contribute 0
    const float wlin   = (j < HID) ? W_lin[j] : 0.0f;

    // gate-B activation: half0 -> tanh(x) = fma(rcp(1+e^{2x}), -2, 1)
    //                    half1 -> sigmoid(x) = rcp(1+e^{-x})
    const float mB   = half ? -1.0f : 2.0f;
    const float sclB = half ?  1.0f : -2.0f;
    const float addB = half ?  0.0f : 1.0f;

    // h state broadcast to all lanes, kept in SGPRs via readlane
    float hs[HID];
#pragma unroll
    for (int k = 0; k < HID; ++k) hs[k] = 0.0f;
    float c = 0.0f;

#define LOADP(XA, XB, TL) do {                                                \
    int _tl = (TL) < SEQ ? (TL) : SEQ - 1;                                    \
    const float4* _xp = (const float4*)(x + ((size_t)_tl * BATCH + b) * INP); \
    XA = _xp[0]; XB = _xp[1];                                                 \
} while (0)

    // ---- x prefetch, distance 4 (static register rotation via unroll-4) ----
    float4 xA0, xB0, xA1, xB1, xA2, xB2, xA3, xB3;
    LOADP(xA0, xB0, 0);
    LOADP(xA1, xB1, 1);
    LOADP(xA2, xB2, 2);
    LOADP(xA3, xB3, 3);

#define STEP(T, XA, XB) do {                                                  \
    float aa0 = bias_a, ab0 = bias_b;                                         \
    aa0 = fmaf((XA).x, wih_a[0], aa0);  ab0 = fmaf((XA).x, wih_b[0], ab0);    \
    aa0 = fmaf((XA).y, wih_a[1], aa0);  ab0 = fmaf((XA).y, wih_b[1], ab0);    \
    aa0 = fmaf((XA).z, wih_a[2], aa0);  ab0 = fmaf((XA).z, wih_b[2], ab0);    \
    aa0 = fmaf((XA).w, wih_a[3], aa0);  ab0 = fmaf((XA).w, wih_b[3], ab0);    \
    float aa1 = 0.0f, ab1 = 0.0f;                                             \
    aa1 = fmaf((XB).x, wih_a[4], aa1);  ab1 = fmaf((XB).x, wih_b[4], ab1);    \
    aa1 = fmaf((XB).y, wih_a[5], aa1);  ab1 = fmaf((XB).y, wih_b[5], ab1);    \
    aa1 = fmaf((XB).z, wih_a[6], aa1);  ab1 = fmaf((XB).z, wih_b[6], ab1);    \
    aa1 = fmaf((XB).w, wih_a[7], aa1);  ab1 = fmaf((XB).w, wih_b[7], ab1);    \
    _Pragma("unroll")                                                         \
    for (int k = 0; k < HID; k += 2) {                                        \
        aa0 = fmaf(hs[k],   whh_a[k],   aa0);                                 \
        ab0 = fmaf(hs[k],   whh_b[k],   ab0);                                 \
        aa1 = fmaf(hs[k+1], whh_a[k+1], aa1);                                 \
        ab1 = fmaf(hs[k+1], whh_b[k+1], ab1);                                 \
    }                                                                         \
    float ga = aa0 + aa1, gb = ab0 + ab1;                                     \
    float Av = sigmoid_f(ga);                                                 \
    float sB = __builtin_amdgcn_rcpf(1.0f + __expf(mB * gb));                 \
    float Bv = fmaf(sB, sclB, addB);                                          \
    float ii, ff, gg, oo;                                                     \
    rep_halves(Av, ii, ff);                                                   \
    rep_halves(Bv, gg, oo);                                                   \
    c = fmaf(ff, c, ii * gg);                                                 \
    float sc = __builtin_amdgcn_rcpf(1.0f + __expf(2.0f * c));                \
    float h  = oo * fmaf(sc, -2.0f, 1.0f);                                    \
    _Pragma("unroll")                                                         \
    for (int k = 0; k < HID; ++k)                                             \
        hs[k] = __uint_as_float((unsigned)__builtin_amdgcn_readlane(          \
                    (int)__float_as_uint(h), k));                             \
    /* output projection: per-lane product, butterfly within 32-lane half */ \
    float p = h * wlin;                                                       \
    p += __shfl_xor(p, 16, 64);                                               \
    p += __shfl_xor(p,  8, 64);                                               \
    p += __shfl_xor(p,  4, 64);                                               \
    p += __shfl_xor(p,  2, 64);                                               \
    p += __shfl_xor(p,  1, 64);                                               \
    if (lane == 0) out[(size_t)(T) * BATCH + b] = p + blin;                   \
} while (0)

    for (int t = 0; t < SEQ; t += 4) {
        STEP(t + 0, xA0, xB0);  LOADP(xA0, xB0, t + 4);
        STEP(t + 1, xA1, xB1);  LOADP(xA1, xB1, t + 5);
        STEP(t + 2, xA2, xB2);  LOADP(xA2, xB2, t + 6);
        STEP(t + 3, xA3, xB3);  LOADP(xA3, xB3, t + 7);
    }
#undef STEP
#undef LOADP
}

extern "C" void kernel_launch(void* const* d_in, const int* in_sizes, int n_in,
                              void* d_out, int out_size, void* d_ws, size_t ws_size,
                              hipStream_t stream) {
    const float* x     = (const float*)d_in[0];
    const float* W_ih  = (const float*)d_in[1];
    const float* W_hh  = (const float*)d_in[2];
    const float* b_ih  = (const float*)d_in[3];
    const float* b_hh  = (const float*)d_in[4];
    const float* W_lin = (const float*)d_in[5];
    const float* b_lin = (const float*)d_in[6];
    float* out = (float*)d_out;

    lstm_chain_kernel<<<dim3(BATCH), dim3(64), 0, stream>>>(
        x, W_ih, W_hh, b_ih, b_hh, W_lin, b_lin, out);
}